// Round 1
// baseline (1750.587 us; speedup 1.0000x reference)
//
#include <hip/hip_runtime.h>
#include <hip/hip_bf16.h>

#define BATCH 64
#define NATOM 128
#define NB    127
#define D0    25
#define D1    50
#define D2    100

// tanh(x) = 1 - 2/(exp(2x)+1); exact limits at +-inf, ~1e-6 rel err.
__device__ __forceinline__ float fast_tanh(float x) {
    float e = __expf(2.0f * x);
    return 1.0f - 2.0f * __builtin_amdgcn_rcpf(e + 1.0f);
}

__global__ __launch_bounds__(128, 2) void feat_kernel(
    const float* __restrict__ coords,
    const int*   __restrict__ types,
    const float* __restrict__ W0, const float* __restrict__ B0,
    const float* __restrict__ W1, const float* __restrict__ B1,
    const float* __restrict__ W2, const float* __restrict__ B2,
    float* __restrict__ out)
{
    // LDS: 51308 + 1524 + 1200 = 54032 B -> 3 blocks/CU
    __shared__ float Gs[NB][D2 + 1];   // stride 101: conflict-free both phases
    __shared__ float Es[NB][3];        // env_a per neighbor
    __shared__ float Ms[3][D2];        // M = E^T G

    const int bn = blockIdx.x;         // b*128 + n
    const int b  = bn >> 7;
    const int n  = bn & 127;
    const int k  = threadIdx.x;        // neighbor slot
    const bool active = (k < NB);

    float h1[D1];

    if (active) {
        const int j = k + (k >= n ? 1 : 0);   // skip self
        const float cx = coords[(b * NATOM + n) * 3 + 0];
        const float cy = coords[(b * NATOM + n) * 3 + 1];
        const float cz = coords[(b * NATOM + n) * 3 + 2];
        const float dx = cx - coords[(b * NATOM + j) * 3 + 0];
        const float dy = cy - coords[(b * NATOM + j) * 3 + 1];
        const float dz = cz - coords[(b * NATOM + j) * 3 + 2];
        const float d2   = dx * dx + dy * dy + dz * dz;
        const float inv  = rsqrtf(d2);        // = 1/d = env_r
        const float inv2 = inv * inv;
        Es[k][0] = dx * inv2;                 // env_a = rij / d^2
        Es[k][1] = dy * inv2;
        Es[k][2] = dz * inv2;

        const int idx = types[n] * 4 + types[j];

        // ---- layer 0: 1 -> 25
        float h0[D0];
        {
            const float* w  = W0 + idx * D0;
            const float* bb = B0 + idx * D0;
            #pragma unroll
            for (int o = 0; o < D0; ++o)
                h0[o] = fast_tanh(w[o] * inv + bb[o]);
        }
        // ---- layer 1: 25 -> 50, residual concat(h0,h0)  (fully unrolled:
        //      h1[o] register-array write needs compile-time index)
        {
            const float* w  = W1 + idx * D1 * D0;
            const float* bb = B1 + idx * D1;
            #pragma unroll
            for (int o = 0; o < D1; ++o) {
                const float* r = w + o * D0;
                float a0 = bb[o], a1 = 0.0f;
                #pragma unroll
                for (int i = 0; i < D0 - 1; i += 2) {
                    a0 += r[i]     * h0[i];
                    a1 += r[i + 1] * h0[i + 1];
                }
                a0 += r[D0 - 1] * h0[D0 - 1];
                h1[o] = fast_tanh(a0 + a1) + h0[o % D0];
            }
        }
        // ---- layer 2: 50 -> 100, tanh part (rolled loop: small I$ footprint;
        //      h1[] reads inside are fully-unrolled constant indices)
        {
            const float* w  = W2 + idx * D2 * D1;
            const float* bb = B2 + idx * D2;
            #pragma unroll 2
            for (int o = 0; o < D2; ++o) {
                const float2* r = (const float2*)(w + o * D1);  // 8B-aligned rows
                float a0 = bb[o], a1 = 0.0f;
                #pragma unroll
                for (int i = 0; i < D1 / 2; ++i) {
                    float2 ww = r[i];
                    a0 += ww.x * h1[2 * i];
                    a1 += ww.y * h1[2 * i + 1];
                }
                Gs[k][o] = fast_tanh(a0 + a1);
            }
            // residual concat(h1,h1): unrolled fix-up keeps h1 in registers
            #pragma unroll
            for (int o = 0; o < D2; ++o)
                Gs[k][o] += h1[o % D1];
        }
    }
    __syncthreads();

    // ---- M[c][m] = sum_k E[k][c] * G[k][m]        (exact collapse:
    //      t = M[:, :4];  out[m][a] = sum_c M[c][m] * M[c][a])
    const int m = threadIdx.x;
    float m0 = 0.0f, m1 = 0.0f, m2 = 0.0f;
    if (m < D2) {
        #pragma unroll 4
        for (int kk = 0; kk < NB; ++kk) {
            const float g = Gs[kk][m];        // stride-1 across lanes
            m0 += Es[kk][0] * g;              // broadcast reads
            m1 += Es[kk][1] * g;
            m2 += Es[kk][2] * g;
        }
        Ms[0][m] = m0; Ms[1][m] = m1; Ms[2][m] = m2;
    }
    __syncthreads();

    if (m < D2) {
        float4 o4;
        o4.x = m0 * Ms[0][0] + m1 * Ms[1][0] + m2 * Ms[2][0];
        o4.y = m0 * Ms[0][1] + m1 * Ms[1][1] + m2 * Ms[2][1];
        o4.z = m0 * Ms[0][2] + m1 * Ms[1][2] + m2 * Ms[2][2];
        o4.w = m0 * Ms[0][3] + m1 * Ms[1][3] + m2 * Ms[2][3];
        reinterpret_cast<float4*>(out)[bn * D2 + m] = o4;   // 16B-aligned
    }
}

extern "C" void kernel_launch(void* const* d_in, const int* in_sizes, int n_in,
                              void* d_out, int out_size, void* d_ws, size_t ws_size,
                              hipStream_t stream) {
    (void)in_sizes; (void)n_in; (void)out_size; (void)d_ws; (void)ws_size;
    const float* coords = (const float*)d_in[0];
    const int*   types  = (const int*)  d_in[1];
    const float* W0 = (const float*)d_in[2];
    const float* B0 = (const float*)d_in[3];
    const float* W1 = (const float*)d_in[4];
    const float* B1 = (const float*)d_in[5];
    const float* W2 = (const float*)d_in[6];
    const float* B2 = (const float*)d_in[7];
    float* out = (float*)d_out;

    feat_kernel<<<BATCH * NATOM, 128, 0, stream>>>(
        coords, types, W0, B0, W1, B1, W2, B2, out);
}

// Round 2
// 1382.267 us; speedup vs baseline: 1.2665x; 1.2665x over previous
//
#include <hip/hip_runtime.h>

#define NATOM 128
#define NB    127
#define D0    25
#define D1    50
#define D2    100
#define GSTRIDE 104   // 100 G + 3 E + 1 pad; rows = 416 B, 16B-aligned

// tanh(x) = 1 - 2/(exp(2x)+1); exact at +-inf, ~1e-6 rel err.
__device__ __forceinline__ float fast_tanh(float x) {
    float e = __expf(2.0f * x);
    return 1.0f - 2.0f * __builtin_amdgcn_rcpf(e + 1.0f);
}

__global__ __launch_bounds__(128, 2) void feat_kernel(
    const float* __restrict__ coords,
    const int*   __restrict__ types,
    const float* __restrict__ W0, const float* __restrict__ B0,
    const float* __restrict__ W1, const float* __restrict__ B1,
    const float* __restrict__ W2, const float* __restrict__ B2,
    float* __restrict__ out)
{
    // 127*104*4 = 52832 B; union adds 1200 B -> 54032 B -> 3 blocks/CU
    __shared__ float Gs[NB][GSTRIDE];
    __shared__ union {
        struct { int St[NB]; int Sj[NB]; } srt;   // dead after phase A start
        float Ms[3][D2];                          // live only in phase 2/3
    } u;

    const int bn = blockIdx.x;     // b*128 + n
    const int b  = bn >> 7;
    const int n  = bn & 127;
    const int k  = threadIdx.x;

    // ---- stable sort of neighbors by type: makes idx wave-uniform so the
    //      per-pair weight loads become same-address L1 broadcasts.
    //      All k-contractions are permutation-invariant -> result identical.
    int tj = 0, j0 = 0;
    if (k < NB) {
        j0 = k + (k >= n ? 1 : 0);          // skip self
        tj = types[j0];
        u.srt.St[k] = tj;
    }
    __syncthreads();
    if (k < NB) {
        int rank = 0;
        #pragma unroll 4
        for (int kk = 0; kk < NB; ++kk) {
            const int t2 = u.srt.St[kk];
            rank += ((t2 < tj) || (t2 == tj && kk < k)) ? 1 : 0;
        }
        u.srt.Sj[rank] = (j0 << 2) | tj;    // pack neighbor id + type
    }
    __syncthreads();

    float h1[D1];   // compile-time-indexed only -> stays in VGPRs

    if (k < NB) {
        const int pj  = u.srt.Sj[k];
        const int jj  = pj >> 2;
        const int idx = (types[n] << 2) | (pj & 3);

        const float cx = coords[(b * NATOM + n) * 3 + 0];
        const float cy = coords[(b * NATOM + n) * 3 + 1];
        const float cz = coords[(b * NATOM + n) * 3 + 2];
        const float dx = cx - coords[(b * NATOM + jj) * 3 + 0];
        const float dy = cy - coords[(b * NATOM + jj) * 3 + 1];
        const float dz = cz - coords[(b * NATOM + jj) * 3 + 2];
        const float d2   = dx * dx + dy * dy + dz * dz;
        const float inv  = rsqrtf(d2);      // 1/d  (= env_r)
        const float inv2 = inv * inv;

        // pack env_a into the Gs row tail (one aligned b128 write)
        {
            float4 e4;
            e4.x = dx * inv2; e4.y = dy * inv2; e4.z = dz * inv2; e4.w = 0.0f;
            *reinterpret_cast<float4*>(&Gs[k][D2]) = e4;
        }

        // ---- layer 0: 1 -> 25 (weight loads are wave-broadcast after sort)
        float h0[D0];
        {
            const float* w  = W0 + idx * D0;
            const float* bb = B0 + idx * D0;
            #pragma unroll
            for (int o = 0; o < D0; ++o)
                h0[o] = fast_tanh(w[o] * inv + bb[o]);
        }

        // ---- layer 1: 25 -> 50 in 5 chunks of 10 (caps live regs ~95)
        {
            const float* w  = W1 + idx * D1 * D0;
            const float* bb = B1 + idx * D1;
            #pragma unroll
            for (int oc = 0; oc < D1; oc += 10) {
                float acc[10];
                #pragma unroll
                for (int uu = 0; uu < 10; ++uu) acc[uu] = bb[oc + uu];
                #pragma unroll
                for (int i = 0; i < D0; ++i) {
                    const float hv = h0[i];
                    #pragma unroll
                    for (int uu = 0; uu < 10; ++uu)
                        acc[uu] += w[(oc + uu) * D0 + i] * hv;
                }
                #pragma unroll
                for (int uu = 0; uu < 10; ++uu)
                    h1[oc + uu] = fast_tanh(acc[uu]) + h0[(oc + uu) % D0];
            }
        }

        // ---- layer 2: 50 -> 100, 4 outputs/iter, rolled (small reg footprint)
        {
            const float* w  = W2 + idx * D2 * D1;
            const float* bb = B2 + idx * D2;
            #pragma unroll 1
            for (int o = 0; o < D2; o += 4) {
                const float2* r0 = (const float2*)(w + (o + 0) * D1); // 8B-aligned
                const float2* r1 = (const float2*)(w + (o + 1) * D1);
                const float2* r2 = (const float2*)(w + (o + 2) * D1);
                const float2* r3 = (const float2*)(w + (o + 3) * D1);
                float a0 = bb[o + 0], a1 = bb[o + 1], a2 = bb[o + 2], a3 = bb[o + 3];
                #pragma unroll
                for (int i = 0; i < D1 / 2; ++i) {
                    const float e0 = h1[2 * i], e1 = h1[2 * i + 1];  // const idx
                    const float2 x0 = r0[i]; a0 += x0.x * e0 + x0.y * e1;
                    const float2 x1 = r1[i]; a1 += x1.x * e0 + x1.y * e1;
                    const float2 x2 = r2[i]; a2 += x2.x * e0 + x2.y * e1;
                    const float2 x3 = r3[i]; a3 += x3.x * e0 + x3.y * e1;
                }
                float4 g4;
                g4.x = fast_tanh(a0); g4.y = fast_tanh(a1);
                g4.z = fast_tanh(a2); g4.w = fast_tanh(a3);
                *reinterpret_cast<float4*>(&Gs[k][o]) = g4;          // aligned
            }
            // residual concat(h1,h1): fully unrolled -> constant h1 indices
            #pragma unroll
            for (int o = 0; o < D2; o += 4) {
                float4 g = *reinterpret_cast<float4*>(&Gs[k][o]);
                g.x += h1[(o + 0) % D1];
                g.y += h1[(o + 1) % D1];
                g.z += h1[(o + 2) % D1];
                g.w += h1[(o + 3) % D1];
                *reinterpret_cast<float4*>(&Gs[k][o]) = g;
            }
        }
    }
    __syncthreads();

    // ---- phase 2: M[c][m] = sum_k E[k][c] * G[k][m]
    //      (einsum collapse: t = M[:, :4]; out[m][a] = sum_c M[c][m]*M[c][a])
    const int m = threadIdx.x;
    float m0 = 0.0f, m1 = 0.0f, m2 = 0.0f;
    if (m < D2) {
        #pragma unroll 4
        for (int kk = 0; kk < NB; ++kk) {
            const float4 e = *reinterpret_cast<const float4*>(&Gs[kk][D2]); // bcast
            const float  g = Gs[kk][m];                 // stride-1 across lanes
            m0 += e.x * g; m1 += e.y * g; m2 += e.z * g;
        }
        u.Ms[0][m] = m0; u.Ms[1][m] = m1; u.Ms[2][m] = m2;
    }
    __syncthreads();

    if (m < D2) {
        float4 o4;
        o4.x = m0 * u.Ms[0][0] + m1 * u.Ms[1][0] + m2 * u.Ms[2][0];
        o4.y = m0 * u.Ms[0][1] + m1 * u.Ms[1][1] + m2 * u.Ms[2][1];
        o4.z = m0 * u.Ms[0][2] + m1 * u.Ms[1][2] + m2 * u.Ms[2][2];
        o4.w = m0 * u.Ms[0][3] + m1 * u.Ms[1][3] + m2 * u.Ms[2][3];
        reinterpret_cast<float4*>(out)[bn * D2 + m] = o4;   // 16B-aligned
    }
}

extern "C" void kernel_launch(void* const* d_in, const int* in_sizes, int n_in,
                              void* d_out, int out_size, void* d_ws, size_t ws_size,
                              hipStream_t stream) {
    (void)in_sizes; (void)n_in; (void)out_size; (void)d_ws; (void)ws_size;
    const float* coords = (const float*)d_in[0];
    const int*   types  = (const int*)  d_in[1];
    const float* W0 = (const float*)d_in[2];
    const float* B0 = (const float*)d_in[3];
    const float* W1 = (const float*)d_in[4];
    const float* B1 = (const float*)d_in[5];
    const float* W2 = (const float*)d_in[6];
    const float* B2 = (const float*)d_in[7];
    float* out = (float*)d_out;

    feat_kernel<<<64 * NATOM, 128, 0, stream>>>(
        coords, types, W0, B0, W1, B1, W2, B2, out);
}

// Round 3
// 1342.909 us; speedup vs baseline: 1.3036x; 1.0293x over previous
//
#include <hip/hip_runtime.h>

#define NATOM 128
#define NB    127
#define D0    25
#define D1    50
#define D2    100
#define GSTRIDE 101   // 101 % 32 = 5, odd -> row-parallel writes conflict-free

// tanh(x) = 1 - 2/(exp(2x)+1); exact at +-inf, ~1e-6 rel err.
__device__ __forceinline__ float fast_tanh(float x) {
    float e = __expf(2.0f * x);
    return 1.0f - 2.0f * __builtin_amdgcn_rcpf(e + 1.0f);
}

__global__ __launch_bounds__(128, 1) void feat_kernel(
    const float* __restrict__ coords,
    const int*   __restrict__ types,
    const float* __restrict__ W0, const float* __restrict__ B0,
    const float* __restrict__ W1, const float* __restrict__ B1,
    const float* __restrict__ W2, const float* __restrict__ B2,
    float* __restrict__ out)
{
    // 127*101*4 = 51308 + 1536 + 1200 = 54044 B -> rounds to 54272 -> 3 blocks/CU
    __shared__ float Gs[NB][GSTRIDE];
    __shared__ float Es[3][128];                  // env_a planes (stride-1 writes)
    __shared__ union {
        struct { int St[NB]; int Sj[NB]; } srt;   // dead after phase 1 starts
        float Ms[3][D2];                          // live only in phase 2/3
    } u;

    const int bn = blockIdx.x;     // b*128 + n
    const int b  = bn >> 7;
    const int n  = bn & 127;
    const int k  = threadIdx.x;

    // ---- stable sort of neighbors by type: makes idx wave-uniform so the
    //      per-pair weight loads become same-address L1 broadcasts.
    //      All k-contractions are permutation-invariant -> result identical.
    int tj = 0, j0 = 0;
    if (k < NB) {
        j0 = k + (k >= n ? 1 : 0);          // skip self
        tj = types[j0];
        u.srt.St[k] = tj;
    }
    __syncthreads();
    if (k < NB) {
        int rank = 0;
        #pragma unroll 4
        for (int kk = 0; kk < NB; ++kk) {
            const int t2 = u.srt.St[kk];    // broadcast read
            rank += ((t2 < tj) || (t2 == tj && kk < k)) ? 1 : 0;
        }
        u.srt.Sj[rank] = (j0 << 2) | tj;    // pack neighbor id + type
    }
    __syncthreads();

    float h1[D1];   // compile-time-indexed only -> must stay in VGPRs

    if (k < NB) {
        const int pj  = u.srt.Sj[k];
        const int jj  = pj >> 2;
        const int idx = (types[n] << 2) | (pj & 3);

        const float cx = coords[(b * NATOM + n) * 3 + 0];
        const float cy = coords[(b * NATOM + n) * 3 + 1];
        const float cz = coords[(b * NATOM + n) * 3 + 2];
        const float dx = cx - coords[(b * NATOM + jj) * 3 + 0];
        const float dy = cy - coords[(b * NATOM + jj) * 3 + 1];
        const float dz = cz - coords[(b * NATOM + jj) * 3 + 2];
        const float d2   = dx * dx + dy * dy + dz * dz;
        const float inv  = rsqrtf(d2);      // 1/d  (= env_r)
        const float inv2 = inv * inv;
        Es[0][k] = dx * inv2;               // stride-1 across lanes: conflict-free
        Es[1][k] = dy * inv2;
        Es[2][k] = dz * inv2;

        // ---- layer 0: 1 -> 25 (weight loads wave-broadcast after sort)
        float h0[D0];
        {
            const float* w  = W0 + idx * D0;
            const float* bb = B0 + idx * D0;
            #pragma unroll
            for (int o = 0; o < D0; ++o)
                h0[o] = fast_tanh(w[o] * inv + bb[o]);
        }

        // ---- layer 1: 25 -> 50 in 5 chunks of 10 (caps live regs)
        {
            const float* w  = W1 + idx * D1 * D0;
            const float* bb = B1 + idx * D1;
            #pragma unroll
            for (int oc = 0; oc < D1; oc += 10) {
                float acc[10];
                #pragma unroll
                for (int uu = 0; uu < 10; ++uu) acc[uu] = bb[oc + uu];
                #pragma unroll
                for (int i = 0; i < D0; ++i) {
                    const float hv = h0[i];
                    #pragma unroll
                    for (int uu = 0; uu < 10; ++uu)
                        acc[uu] += w[(oc + uu) * D0 + i] * hv;
                }
                #pragma unroll
                for (int uu = 0; uu < 10; ++uu)
                    h1[oc + uu] = fast_tanh(acc[uu]) + h0[(oc + uu) % D0];
            }
        }

        // ---- layer 2: 50 -> 100, 4 outputs/iter, rolled (small reg footprint)
        {
            const float* w  = W2 + idx * D2 * D1;
            const float* bb = B2 + idx * D2;
            #pragma unroll 1
            for (int o = 0; o < D2; o += 4) {
                const float2* r0 = (const float2*)(w + (o + 0) * D1); // 8B-aligned
                const float2* r1 = (const float2*)(w + (o + 1) * D1);
                const float2* r2 = (const float2*)(w + (o + 2) * D1);
                const float2* r3 = (const float2*)(w + (o + 3) * D1);
                float a0 = bb[o + 0], a1 = bb[o + 1], a2 = bb[o + 2], a3 = bb[o + 3];
                #pragma unroll
                for (int i = 0; i < D1 / 2; ++i) {
                    const float e0 = h1[2 * i], e1 = h1[2 * i + 1];  // const idx
                    const float2 x0 = r0[i]; a0 += x0.x * e0 + x0.y * e1;
                    const float2 x1 = r1[i]; a1 += x1.x * e0 + x1.y * e1;
                    const float2 x2 = r2[i]; a2 += x2.x * e0 + x2.y * e1;
                    const float2 x3 = r3[i]; a3 += x3.x * e0 + x3.y * e1;
                }
                Gs[k][o + 0] = fast_tanh(a0);   // stride-101 rows: conflict-free
                Gs[k][o + 1] = fast_tanh(a1);
                Gs[k][o + 2] = fast_tanh(a2);
                Gs[k][o + 3] = fast_tanh(a3);
            }
            // residual concat(h1,h1): fully unrolled -> constant h1 indices
            #pragma unroll
            for (int o = 0; o < D2; ++o)
                Gs[k][o] += h1[o % D1];
        }
    }
    __syncthreads();

    // ---- phase 2: M[c][m] = sum_k E[k][c] * G[k][m]
    //      (einsum collapse: t = M[:, :4]; out[m][a] = sum_c M[c][m]*M[c][a])
    const int m = threadIdx.x;
    float m0 = 0.0f, m1 = 0.0f, m2 = 0.0f;
    if (m < D2) {
        #pragma unroll 4
        for (int kk = 0; kk < NB; ++kk) {
            const float g = Gs[kk][m];          // stride-1 across lanes: free
            m0 += Es[0][kk] * g;                // broadcast reads: free
            m1 += Es[1][kk] * g;
            m2 += Es[2][kk] * g;
        }
        u.Ms[0][m] = m0; u.Ms[1][m] = m1; u.Ms[2][m] = m2;
    }
    __syncthreads();

    if (m < D2) {
        float4 o4;
        o4.x = m0 * u.Ms[0][0] + m1 * u.Ms[1][0] + m2 * u.Ms[2][0];
        o4.y = m0 * u.Ms[0][1] + m1 * u.Ms[1][1] + m2 * u.Ms[2][1];
        o4.z = m0 * u.Ms[0][2] + m1 * u.Ms[1][2] + m2 * u.Ms[2][2];
        o4.w = m0 * u.Ms[0][3] + m1 * u.Ms[1][3] + m2 * u.Ms[2][3];
        reinterpret_cast<float4*>(out)[bn * D2 + m] = o4;   // 16B-aligned
    }
}

extern "C" void kernel_launch(void* const* d_in, const int* in_sizes, int n_in,
                              void* d_out, int out_size, void* d_ws, size_t ws_size,
                              hipStream_t stream) {
    (void)in_sizes; (void)n_in; (void)out_size; (void)d_ws; (void)ws_size;
    const float* coords = (const float*)d_in[0];
    const int*   types  = (const int*)  d_in[1];
    const float* W0 = (const float*)d_in[2];
    const float* B0 = (const float*)d_in[3];
    const float* W1 = (const float*)d_in[4];
    const float* B1 = (const float*)d_in[5];
    const float* W2 = (const float*)d_in[6];
    const float* B2 = (const float*)d_in[7];
    float* out = (float*)d_out;

    feat_kernel<<<64 * NATOM, 128, 0, stream>>>(
        coords, types, W0, B0, W1, B1, W2, B2, out);
}